// Round 12
// baseline (452.820 us; speedup 1.0000x reference)
//
#include <hip/hip_runtime.h>
#include <hip/hip_fp16.h>
#include <math.h>

#define NFEAT 128
#define CAP 64        // padded-CSR slots per node; degree ~Poisson(16), P(>=64) ~ 1e-14
#define BINSHIFT 7    // 128 nodes per bin; requires N <= 131072 (N = 100000 here)
#define GB 256        // build grid (hist/scatter blocks)

// edge record: .x = src index, .y = weight bits. After k_premul, .y holds dis[src]*w.
// R11: slots [cnt,64) are ZERO (src=0, w=0) -> gather needs no bounds clamps/gates.
typedef int2 EdgeRec;

// fp16 row helpers: t1/t2 stored as __half (R6: halves gather bytes; accum stays fp32)
__device__ inline float4 h4_to_f4(uint2 u) {
  __half2 lo = *(__half2*)&u.x;
  __half2 hi = *(__half2*)&u.y;
  float2 a = __half22float2(lo), b = __half22float2(hi);
  return make_float4(a.x, a.y, b.x, b.y);
}
__device__ inline uint2 f4_to_h4(float4 v) {
  __half2 lo = __floats2half2_rn(v.x, v.y);
  __half2 hi = __floats2half2_rn(v.z, v.w);
  uint2 r; r.x = *(unsigned*)&lo; r.y = *(unsigned*)&hi; return r;
}

// ================= counting-sort CSR build — ZERO global atomics =================

// ---- phase 1: per-block histogram of dst bins (writes transposed: [bin][block]) ----
__global__ __launch_bounds__(256) void k_hist(const int* __restrict__ dst,
                                              unsigned* __restrict__ histG,
                                              int E, int EPB, int nbins) {
  __shared__ unsigned lh[1024];
  for (int i = threadIdx.x; i < nbins; i += 256) lh[i] = 0;
  __syncthreads();
  int start = blockIdx.x * EPB;
  int end = start + EPB; if (end > E) end = E;
  for (int e = start + threadIdx.x; e < end; e += 256)
    atomicAdd(&lh[dst[e] >> BINSHIFT], 1u);
  __syncthreads();
  for (int i = threadIdx.x; i < nbins; i += 256)
    histG[(size_t)i * GB + blockIdx.x] = lh[i];
}

// ---- phase 2a: per-bin totals (wave per bin, coalesced uint4) ----
__global__ __launch_bounds__(256) void k_scanT(const unsigned* __restrict__ histG,
                                               unsigned* __restrict__ binTot, int nbins) {
  int wave = threadIdx.x >> 6;
  int lane = threadIdx.x & 63;
  int bin = blockIdx.x * 4 + wave;
  if (bin >= nbins) return;
  uint4 v = *(const uint4*)(histG + (size_t)bin * GB + lane * 4);
  int s = (int)(v.x + v.y + v.z + v.w);
#pragma unroll
  for (int off = 32; off > 0; off >>= 1) s += __shfl_down(s, off, 64);
  if (lane == 0) binTot[bin] = (unsigned)s;
}

// ---- phase 2b: exclusive scan of bin totals (one block, 3KB in LDS) ----
__global__ __launch_bounds__(1024) void k_scanB(const unsigned* __restrict__ binTot,
                                                unsigned* __restrict__ binBase, int nbins) {
  __shared__ unsigned tot[1024];
  int b = threadIdx.x;
  tot[b] = (b < nbins) ? binTot[b] : 0;
  __syncthreads();
  for (int off = 1; off < 1024; off <<= 1) {
    unsigned v = (b >= off) ? tot[b - off] : 0;
    __syncthreads();
    tot[b] += v;
    __syncthreads();
  }
  if (b < nbins) binBase[b] = (b == 0) ? 0u : tot[b - 1];
  if (b == 0) binBase[nbins] = tot[1023];
}

// ---- phase 2c: rewrite histG to per-(block,bin) global offsets (wave per bin) ----
__global__ __launch_bounds__(256) void k_scanC(unsigned* __restrict__ histG,
                                               const unsigned* __restrict__ binBase,
                                               int nbins) {
  int wave = threadIdx.x >> 6;
  int lane = threadIdx.x & 63;
  int bin = blockIdx.x * 4 + wave;
  if (bin >= nbins) return;
  uint4 v = *(const uint4*)(histG + (size_t)bin * GB + lane * 4);
  unsigned i1 = v.x + v.y;
  unsigned i2 = i1 + v.z;
  unsigned i3 = i2 + v.w;
  int inc = (int)i3;
#pragma unroll
  for (int off = 1; off < 64; off <<= 1) {
    int t = __shfl_up(inc, off, 64);
    if (lane >= off) inc += t;
  }
  unsigned base = binBase[bin] + (unsigned)inc - i3;  // exclusive lane prefix
  uint4 o;
  o.x = base;
  o.y = base + v.x;
  o.z = base + i1;
  o.w = base + i2;
  *(uint4*)(histG + (size_t)bin * GB + lane * 4) = o;
}

// ---- phase 3: scatter edges to bin-sorted order (LDS ranks only) ----
// packed record: .x = src | (dstLow7 << 24)   (src < 2^24), .y = weight bits
__global__ __launch_bounds__(256) void k_scatter(const int* __restrict__ src,
                                                 const int* __restrict__ dst,
                                                 const float* __restrict__ ew,
                                                 const unsigned* __restrict__ histG,
                                                 uint2* __restrict__ sorted,
                                                 int E, int EPB, int nbins) {
  __shared__ unsigned lrank[1024];
  __shared__ unsigned lbase[1024];
  for (int i = threadIdx.x; i < nbins; i += 256) {
    lrank[i] = 0;
    lbase[i] = histG[(size_t)i * GB + blockIdx.x];
  }
  __syncthreads();
  int start = blockIdx.x * EPB;
  int end = start + EPB; if (end > E) end = E;
  for (int e = start + threadIdx.x; e < end; e += 256) {
    int d = dst[e];
    int bin = d >> BINSHIFT;
    unsigned r = atomicAdd(&lrank[bin], 1u);
    uint2 rec;
    rec.x = (unsigned)src[e] | ((unsigned)(d & 127) << 24);
    rec.y = __float_as_uint(ew[e]);
    sorted[lbase[bin] + r] = rec;
  }
}

// ---- phase 4: per-bin padded-CSR fill + cnt + dis, LDS only. R11: zero-pads [cnt,64) ----
__global__ __launch_bounds__(256) void k_csr(const uint2* __restrict__ sorted,
                                             const unsigned* __restrict__ binBase,
                                             unsigned* __restrict__ cnt,
                                             EdgeRec* __restrict__ ep,
                                             float* __restrict__ dis, int N) {
  int bin = blockIdx.x;
  __shared__ unsigned lcnt[128];
  __shared__ float lsum[128];
  if (threadIdx.x < 128) { lcnt[threadIdx.x] = 0; lsum[threadIdx.x] = 0.f; }
  __syncthreads();
  unsigned s0 = binBase[bin], s1 = binBase[bin + 1];
  int node0 = bin << BINSHIFT;
  for (unsigned e = s0 + threadIdx.x; e < s1; e += 256) {
    uint2 rec = sorted[e];
    int dlow = rec.x >> 24;
    int srcn = rec.x & 0xFFFFFF;
    unsigned slot = atomicAdd(&lcnt[dlow], 1u);
    if (slot < CAP) {
      EdgeRec r; r.x = srcn; r.y = (int)rec.y;
      ep[(size_t)(node0 + dlow) * CAP + slot] = r;
    }
    atomicAdd(&lsum[dlow], __uint_as_float(rec.y));
  }
  __syncthreads();
  // zero-pad slots [cnt, 64): gather kernels then need no bounds clamps (pad w = 0)
  for (int i = threadIdx.x; i < 128 * CAP; i += 256) {
    int dlow = i >> 6;
    int slot = i & (CAP - 1);
    int node = node0 + dlow;
    unsigned c = lcnt[dlow]; if (c > CAP) c = CAP;
    if (node < N && (unsigned)slot >= c) {
      EdgeRec zr; zr.x = 0; zr.y = 0;
      ep[(size_t)node * CAP + slot] = zr;
    }
  }
  if (threadIdx.x < 128) {
    int node = node0 + threadIdx.x;
    if (node < N) {
      unsigned c = lcnt[threadIdx.x]; if (c > CAP) c = CAP;
      cnt[node] = c;
      dis[node] = 1.0f / sqrtf(1.0f + lsum[threadIdx.x]);
    }
  }
}

// fold dis[src] into stored edge weight (pad slots untouched: lane < cnt only)
__global__ __launch_bounds__(256) void k_premul(EdgeRec* __restrict__ ep,
                                                const unsigned* __restrict__ cnt,
                                                const float* __restrict__ dis, int N) {
  int wave = threadIdx.x >> 6;
  int lane = threadIdx.x & 63;
  int node = blockIdx.x * 4 + wave;
  if (node >= N) return;
  int c = (int)cnt[node];
  if (lane < c) {
    int e = node * CAP + lane;
    EdgeRec r = ep[e];
    r.y = __float_as_int(dis[r.x] * __int_as_float(r.y));
    ep[e] = r;
  }
}

// ---------------- pure GEMM layer-1 ----------------

__global__ __launch_bounds__(1024) void k_gemm1(const float* __restrict__ X,
                                                const float* __restrict__ W,
                                                __half* __restrict__ Y,
                                                int N, int numTiles) {
  __shared__ float sW[128 * 128];  // 64 KB, [k][c]
  __shared__ float sX[128 * 128];  // 64 KB, [r][k ^ ((r>>2)&7)<<2]
  int t = threadIdx.x;
  int wave = __builtin_amdgcn_readfirstlane(t >> 6);  // 0..15
  int lane = t & 63;
  int lr = (lane >> 3) & 7;
  int lc = lane & 7;
  int wr = wave >> 2;  // 0..3
  int wc = wave & 3;   // 0..3

  {
    const float4* W4 = (const float4*)W;
    float4* sW4 = (float4*)sW;
    for (int i = t; i < 4096; i += 1024) sW4[i] = W4[i];
  }

  const float4* X4 = (const float4*)X;
  int grmax = N - 1;
  int r0 = wr * 32 + lr * 4;   // 4 rows per thread
  int c0 = wc * 32 + lc * 4;   // 4 cols per thread
  int swzk = ((r0 >> 2) & 7) << 2;

  for (int tile = blockIdx.x; tile < numTiles; tile += gridDim.x) {
    int rowBase = tile * 128;
    __syncthreads();  // prior tile's sX reads done
    {
      int kg = t & 31;
      int rb = t >> 5;
#pragma unroll
      for (int p = 0; p < 4; p++) {
        int r = rb + 32 * p;
        int gr = rowBase + r; if (gr > grmax) gr = grmax;
        float4 v = X4[(size_t)gr * 32 + kg];
        int swz = ((r >> 2) & 7) << 2;
        *(float4*)(&sX[r * 128 + ((kg * 4) ^ swz)]) = v;
      }
    }
    __syncthreads();

    float4 acc[4];
#pragma unroll
    for (int i = 0; i < 4; i++) acc[i] = make_float4(0.f, 0.f, 0.f, 0.f);

#pragma unroll 1
    for (int kg = 0; kg < 32; kg++) {
      int kk0 = kg * 4;
      float4 xf[4];
#pragma unroll
      for (int i = 0; i < 4; i++)
        xf[i] = *(const float4*)(&sX[(r0 + i) * 128 + (kk0 ^ swzk)]);
      float4 wf[4];
#pragma unroll
      for (int kk = 0; kk < 4; kk++)
        wf[kk] = *(const float4*)(&sW[(kk0 + kk) * 128 + c0]);
#pragma unroll
      for (int kk = 0; kk < 4; kk++) {
#pragma unroll
        for (int i = 0; i < 4; i++) {
          float xs = (&xf[i].x)[kk];
          acc[i].x = fmaf(xs, wf[kk].x, acc[i].x);
          acc[i].y = fmaf(xs, wf[kk].y, acc[i].y);
          acc[i].z = fmaf(xs, wf[kk].z, acc[i].z);
          acc[i].w = fmaf(xs, wf[kk].w, acc[i].w);
        }
      }
    }

#pragma unroll
    for (int i = 0; i < 4; i++) {
      int row = rowBase + r0 + i;
      if (row < N)
        *(uint2*)(Y + (size_t)row * 128 + c0) = f4_to_h4(acc[i]);
    }
  }
}

// ---------------- fused: layer-1 aggregate -> LDS tile -> GEMM by W2 ----------------
// R11 gather: full wave per node; edge recs read at wave-uniform (scalar/SMEM)
// addresses; each row-load instruction covers 2 edges (lane<32 = edge A, >=32 = B);
// zero-padded slots remove all bounds clamps and weight gates. Per-edge VALU ~8 (was ~26).

__global__ __launch_bounds__(1024) void k_aggemm(const __half* __restrict__ H,
                                                 const unsigned* __restrict__ cntA,
                                                 const EdgeRec* __restrict__ ep,
                                                 const float* __restrict__ dis,
                                                 const float* __restrict__ bias,
                                                 const float* __restrict__ Wm,
                                                 __half* __restrict__ Y,
                                                 int N, int numTiles) {
  __shared__ float sW[128 * 128];     // 64 KB, [k][c]
  __shared__ float sX[2][64 * 128];   // 2 x 32 KB, [r][k ^ ((r>>2)&7)<<2]
  int t = threadIdx.x;
  int wave = __builtin_amdgcn_readfirstlane(t >> 6);  // 0..15
  int lane = t & 63;

  {
    const float4* W4 = (const float4*)Wm;
    float4* sW4 = (float4*)sW;
    for (int i = t; i < 4096; i += 1024) sW4[i] = W4[i];
  }
  __syncthreads();

  int gw = wave;
  int hi = lane >> 5;
  int l32 = lane & 31;
  int mw = wave - 12;
  int wr = (mw >> 1) & 1;
  int wc = mw & 1;
  int lr = (lane >> 3) & 7;
  int lc = lane & 7;
  int rB = wr * 32 + lr * 4;
  int cA = wc * 64 + lc * 4;
  int cB = cA + 32;
  int swzm = lr << 2;

  for (int it = 0;; it++) {
    int gtile = blockIdx.x + it * gridDim.x;
    int mtile = gtile - (int)gridDim.x;
    bool anyG = gtile < numTiles;
    bool anyM = (it >= 1) && (mtile < numTiles);
    if (!anyG && !anyM) break;

    if (wave < 12) {
      if (anyG) {
        float* buf = sX[it & 1];
        int tileBase = gtile * 64;
        for (int s = gw; s < 64; s += 12) {
          int node = tileBase + s;
          if (node >= N) continue;
          int cnt = (int)cntA[node];         // wave-uniform -> s_load
          int beg = node * CAP;
          int emax = beg + CAP - 1;

          float4 acc = make_float4(0.f, 0.f, 0.f, 0.f);
          if (cnt > 0) {
            // uniform rec indices -> scalar loads; pad recs (w=0) kill gating
            EdgeRec e0[4], e1[4];
            uint2 hA0, hB0;
#define LDE(d_, idx_) { int q_ = beg + (idx_); q_ = q_ <= emax ? q_ : emax; d_ = ep[q_]; }
            LDE(e0[0], 0) LDE(e0[1], 1) LDE(e0[2], 2) LDE(e0[3], 3)
            LDE(e1[0], 4) LDE(e1[1], 5) LDE(e1[2], 6) LDE(e1[3], 7)
            {
              int sA = hi ? e0[1].x : e0[0].x;
              int sB = hi ? e0[3].x : e0[2].x;
              hA0 = *(const uint2*)(H + (size_t)sA * 128 + 4 * l32);
              hB0 = *(const uint2*)(H + (size_t)sB * 128 + 4 * l32);
            }
            for (int p = 0; p < cnt; p += 4) {
              EdgeRec e2[4];
              LDE(e2[0], p + 8) LDE(e2[1], p + 9) LDE(e2[2], p + 10) LDE(e2[3], p + 11)
              int nA = hi ? e1[1].x : e1[0].x;
              int nB = hi ? e1[3].x : e1[2].x;
              uint2 hA1 = *(const uint2*)(H + (size_t)nA * 128 + 4 * l32);
              uint2 hB1 = *(const uint2*)(H + (size_t)nB * 128 + 4 * l32);
              float wA = __int_as_float(hi ? e0[1].y : e0[0].y);
              float wB = __int_as_float(hi ? e0[3].y : e0[2].y);
              float4 a = h4_to_f4(hA0);
              float4 b = h4_to_f4(hB0);
              acc.x = fmaf(wA, a.x, acc.x);
              acc.y = fmaf(wA, a.y, acc.y);
              acc.z = fmaf(wA, a.z, acc.z);
              acc.w = fmaf(wA, a.w, acc.w);
              acc.x = fmaf(wB, b.x, acc.x);
              acc.y = fmaf(wB, b.y, acc.y);
              acc.z = fmaf(wB, b.z, acc.z);
              acc.w = fmaf(wB, b.w, acc.w);
#pragma unroll
              for (int q = 0; q < 4; q++) { e0[q] = e1[q]; e1[q] = e2[q]; }
              hA0 = hA1; hB0 = hB1;
            }
#undef LDE
          }
          // combine edge-A/edge-B halves
          acc.x += __shfl_xor(acc.x, 32, 64);
          acc.y += __shfl_xor(acc.y, 32, 64);
          acc.z += __shfl_xor(acc.z, 32, 64);
          acc.w += __shfl_xor(acc.w, 32, 64);
          if (hi == 0) {
            float ds = dis[node];
            float4 hn = h4_to_f4(*(const uint2*)(H + (size_t)node * 128 + 4 * l32));
            acc.x = fmaf(ds, hn.x, acc.x);
            acc.y = fmaf(ds, hn.y, acc.y);
            acc.z = fmaf(ds, hn.z, acc.z);
            acc.w = fmaf(ds, hn.w, acc.w);
            float4 bv = *(const float4*)(bias + 4 * l32);
            float4 o;
            o.x = fmaf(ds, acc.x, bv.x); o.x = o.x > 0.f ? o.x : 0.f;
            o.y = fmaf(ds, acc.y, bv.y); o.y = o.y > 0.f ? o.y : 0.f;
            o.z = fmaf(ds, acc.z, bv.z); o.z = o.z > 0.f ? o.z : 0.f;
            o.w = fmaf(ds, acc.w, bv.w); o.w = o.w > 0.f ? o.w : 0.f;
            int swz = ((s >> 2) & 7) << 2;
            *(float4*)(&buf[s * 128 + ((4 * l32) ^ swz)]) = o;
          }
        }
      }
    } else {
      if (anyM) {
        const float* buf = sX[(it - 1) & 1];
        float4 accA[4], accB[4];
#pragma unroll
        for (int i = 0; i < 4; i++) {
          accA[i] = make_float4(0.f, 0.f, 0.f, 0.f);
          accB[i] = make_float4(0.f, 0.f, 0.f, 0.f);
        }
#pragma unroll 2
        for (int kg = 0; kg < 32; kg++) {
          int kk0 = kg * 4;
          float4 xf[4];
#pragma unroll
          for (int i = 0; i < 4; i++)
            xf[i] = *(const float4*)(&buf[(rB + i) * 128 + (kk0 ^ swzm)]);
#pragma unroll
          for (int kk = 0; kk < 4; kk++) {
            float4 wA = *(const float4*)(&sW[(kk0 + kk) * 128 + cA]);
            float4 wB = *(const float4*)(&sW[(kk0 + kk) * 128 + cB]);
#pragma unroll
            for (int i = 0; i < 4; i++) {
              float xs = (&xf[i].x)[kk];
              accA[i].x = fmaf(xs, wA.x, accA[i].x);
              accA[i].y = fmaf(xs, wA.y, accA[i].y);
              accA[i].z = fmaf(xs, wA.z, accA[i].z);
              accA[i].w = fmaf(xs, wA.w, accA[i].w);
              accB[i].x = fmaf(xs, wB.x, accB[i].x);
              accB[i].y = fmaf(xs, wB.y, accB[i].y);
              accB[i].z = fmaf(xs, wB.z, accB[i].z);
              accB[i].w = fmaf(xs, wB.w, accB[i].w);
            }
          }
        }
        int rowBase = mtile * 64;
#pragma unroll
        for (int i = 0; i < 4; i++) {
          int row = rowBase + rB + i;
          if (row < N) {
            *(uint2*)(Y + (size_t)row * 128 + cA) = f4_to_h4(accA[i]);
            *(uint2*)(Y + (size_t)row * 128 + cB) = f4_to_h4(accB[i]);
          }
        }
      }
    }
    __syncthreads();
  }
}

// ---- final aggregate fused with W3 dot: z[node] = relu(dis*(agg + dis*h_own) + b2) . W3 ----
// R11: same scalar-rec / 2-edges-per-load structure. Wave per node, 4 nodes/block.

__global__ __launch_bounds__(256) void k_agg_final(const __half* __restrict__ H,
                                                   const unsigned* __restrict__ cntA,
                                                   const EdgeRec* __restrict__ ep,
                                                   const float* __restrict__ dis,
                                                   const float* __restrict__ bias,
                                                   const float* __restrict__ W3,
                                                   float* __restrict__ z, int N) {
  int wave = __builtin_amdgcn_readfirstlane(threadIdx.x >> 6);
  int lane = threadIdx.x & 63;
  int hi = lane >> 5;
  int l32 = lane & 31;
  int node = blockIdx.x * 4 + wave;
  if (node >= N) return;
  int cnt = (int)cntA[node];          // wave-uniform -> s_load
  int beg = node * CAP;
  int emax = beg + CAP - 1;

  float4 acc = make_float4(0.f, 0.f, 0.f, 0.f);
  if (cnt > 0) {
    EdgeRec e0[4], e1[4];
    uint2 hA0, hB0;
#define LDE(d_, idx_) { int q_ = beg + (idx_); q_ = q_ <= emax ? q_ : emax; d_ = ep[q_]; }
    LDE(e0[0], 0) LDE(e0[1], 1) LDE(e0[2], 2) LDE(e0[3], 3)
    LDE(e1[0], 4) LDE(e1[1], 5) LDE(e1[2], 6) LDE(e1[3], 7)
    {
      int sA = hi ? e0[1].x : e0[0].x;
      int sB = hi ? e0[3].x : e0[2].x;
      hA0 = *(const uint2*)(H + (size_t)sA * 128 + 4 * l32);
      hB0 = *(const uint2*)(H + (size_t)sB * 128 + 4 * l32);
    }
    for (int p = 0; p < cnt; p += 4) {
      EdgeRec e2[4];
      LDE(e2[0], p + 8) LDE(e2[1], p + 9) LDE(e2[2], p + 10) LDE(e2[3], p + 11)
      int nA = hi ? e1[1].x : e1[0].x;
      int nB = hi ? e1[3].x : e1[2].x;
      uint2 hA1 = *(const uint2*)(H + (size_t)nA * 128 + 4 * l32);
      uint2 hB1 = *(const uint2*)(H + (size_t)nB * 128 + 4 * l32);
      float wA = __int_as_float(hi ? e0[1].y : e0[0].y);
      float wB = __int_as_float(hi ? e0[3].y : e0[2].y);
      float4 a = h4_to_f4(hA0);
      float4 b = h4_to_f4(hB0);
      acc.x = fmaf(wA, a.x, acc.x);
      acc.y = fmaf(wA, a.y, acc.y);
      acc.z = fmaf(wA, a.z, acc.z);
      acc.w = fmaf(wA, a.w, acc.w);
      acc.x = fmaf(wB, b.x, acc.x);
      acc.y = fmaf(wB, b.y, acc.y);
      acc.z = fmaf(wB, b.z, acc.z);
      acc.w = fmaf(wB, b.w, acc.w);
#pragma unroll
      for (int q = 0; q < 4; q++) { e0[q] = e1[q]; e1[q] = e2[q]; }
      hA0 = hA1; hB0 = hB1;
    }
#undef LDE
  }
  acc.x += __shfl_xor(acc.x, 32, 64);
  acc.y += __shfl_xor(acc.y, 32, 64);
  acc.z += __shfl_xor(acc.z, 32, 64);
  acc.w += __shfl_xor(acc.w, 32, 64);
  if (hi == 0) {
    float ds = dis[node];
    float4 hn = h4_to_f4(*(const uint2*)(H + (size_t)node * 128 + 4 * l32));
    acc.x = fmaf(ds, hn.x, acc.x);
    acc.y = fmaf(ds, hn.y, acc.y);
    acc.z = fmaf(ds, hn.z, acc.z);
    acc.w = fmaf(ds, hn.w, acc.w);
    float4 bv = *(const float4*)(bias + 4 * l32);
    float4 w3v = *(const float4*)(W3 + 4 * l32);
    float o, pdot = 0.f;
    o = fmaf(ds, acc.x, bv.x); o = o > 0.f ? o : 0.f; pdot = fmaf(o, w3v.x, pdot);
    o = fmaf(ds, acc.y, bv.y); o = o > 0.f ? o : 0.f; pdot = fmaf(o, w3v.y, pdot);
    o = fmaf(ds, acc.z, bv.z); o = o > 0.f ? o : 0.f; pdot = fmaf(o, w3v.z, pdot);
    o = fmaf(ds, acc.w, bv.w); o = o > 0.f ? o : 0.f; pdot = fmaf(o, w3v.w, pdot);
#pragma unroll
    for (int off = 16; off > 0; off >>= 1) pdot += __shfl_down(pdot, off, 32);
    if (l32 == 0) z[node] = pdot;
  }
}

// ---------------- scalar final layer: out = relu(dis*(agg_z + dis*z[n]) + b3) ----------------

__global__ void k_aggs(const float* __restrict__ z, const unsigned* __restrict__ cntA,
                       const EdgeRec* __restrict__ ep, const float* __restrict__ dis,
                       const float* __restrict__ b3, float* __restrict__ out, int N) {
  int n = blockIdx.x * blockDim.x + threadIdx.x;
  if (n >= N) return;
  int cnt = (int)cntA[n];
  float dsn = dis[n];
  float acc = dsn * z[n];  // self-loop
  int beg = n * CAP;
#pragma unroll 4
  for (int e = beg; e < beg + cnt; e++) {
    EdgeRec p = ep[e];
    acc = fmaf(__int_as_float(p.y), z[p.x], acc);
  }
  acc = fmaf(dsn, acc, b3[0]);
  out[n] = acc > 0.f ? acc : 0.f;
}

// ---------------- launch ----------------

extern "C" void kernel_launch(void* const* d_in, const int* in_sizes, int n_in,
                              void* d_out, int out_size, void* d_ws, size_t ws_size,
                              hipStream_t stream) {
  const float* x  = (const float*)d_in[0];
  const int*   ei = (const int*)d_in[1];
  const float* ew = (const float*)d_in[2];
  const float* W1 = (const float*)d_in[3];
  const float* b1 = (const float*)d_in[4];
  const float* W2 = (const float*)d_in[5];
  const float* b2 = (const float*)d_in[6];
  const float* W3 = (const float*)d_in[7];
  const float* b3 = (const float*)d_in[8];
  int N = in_sizes[0] / NFEAT;
  int E = in_sizes[2];
  const int* srcp = ei;
  const int* dstp = ei + E;

  char* p = (char*)d_ws;
  auto carve = [&](size_t bytes) -> void* {
    void* r = (void*)p;
    p += (bytes + 511) & ~(size_t)511;
    return r;
  };
  int nbins = (N + 127) >> BINSHIFT;     // 782 for N=100000 (must be <= 1024)
  unsigned* cnt     = (unsigned*)carve(sizeof(unsigned) * N);
  float*    dis     = (float*)carve(sizeof(float) * N);
  EdgeRec*  ep      = (EdgeRec*)carve(sizeof(EdgeRec) * ((size_t)N * CAP + 64));
  __half*   t1      = (__half*)carve(sizeof(__half) * (size_t)N * NFEAT);
  __half*   t2      = (__half*)carve(sizeof(__half) * (size_t)N * NFEAT);
  float*    z       = (float*)carve(sizeof(float) * N);
  unsigned* histG   = (unsigned*)carve(sizeof(unsigned) * (size_t)GB * nbins);
  unsigned* binTot  = (unsigned*)carve(sizeof(unsigned) * nbins);
  unsigned* binBase = (unsigned*)carve(sizeof(unsigned) * (nbins + 1));
  uint2*    sorted  = (uint2*)carve(sizeof(uint2) * (size_t)E);

  int gN = (N + 255) / 256;
  int numTiles128 = (N + 127) / 128;
  int numTiles64  = (N + 63) / 64;
  int GG = 256;                      // 1 block/CU grids
  int EPB = (E + GB - 1) / GB;       // edges per build block
  int gS = (nbins + 3) / 4;          // scanT/scanC: wave per bin
  int gP = (N + 3) / 4;              // k_premul / k_agg_final: 4 nodes/block

  // counting-sort CSR build (no global atomics; R10 parallel coalesced scan)
  k_hist<<<GB, 256, 0, stream>>>(dstp, histG, E, EPB, nbins);
  k_scanT<<<gS, 256, 0, stream>>>(histG, binTot, nbins);
  k_scanB<<<1, 1024, 0, stream>>>(binTot, binBase, nbins);
  k_scanC<<<gS, 256, 0, stream>>>(histG, binBase, nbins);
  k_scatter<<<GB, 256, 0, stream>>>(srcp, dstp, ew, histG, sorted, E, EPB, nbins);
  k_csr<<<nbins, 256, 0, stream>>>(sorted, binBase, cnt, ep, dis, N);
  // layer-1 GEMM
  k_gemm1<<<GG, 1024, 0, stream>>>(x, W1, t1, N, numTiles128);
  // fold dis[src] into edge weights (used by all three aggregate kernels)
  k_premul<<<gP, 256, 0, stream>>>(ep, cnt, dis, N);
  // layer-1 aggregate fused with layer-2 GEMM (12 gather + 4 gemm waves)
  k_aggemm<<<GG, 1024, 0, stream>>>(t1, cnt, ep, dis, b1, W2, t2, N, numTiles64);
  // layer-2 aggregate + W3 dot
  k_agg_final<<<gP, 256, 0, stream>>>(t2, cnt, ep, dis, b2, W3, z, N);
  // layer-3 scalar aggregate
  k_aggs<<<gN, 256, 0, stream>>>(z, cnt, ep, dis, b3, (float*)d_out, N);
}

// Round 13
// 428.989 us; speedup vs baseline: 1.0556x; 1.0556x over previous
//
#include <hip/hip_runtime.h>
#include <hip/hip_fp16.h>
#include <math.h>

#define NFEAT 128
#define CAP 64        // padded-CSR slots per node; degree ~Poisson(16), P(>=64) ~ 1e-14
#define BINSHIFT 7    // 128 nodes per bin; requires N <= 131072 (N = 100000 here)
#define GB 256        // build grid (hist/scatter blocks)

// edge record: .x = src index, .y = weight bits. After k_premul, .y holds dis[src]*w.
// Slots [cnt,64) are ZERO (src=0, w=0) -> gather needs no weight gates; bounds are a
// single min() to slot 63 (zero whenever cnt<64).
typedef int2 EdgeRec;

// fp16 row helpers: t1/t2 stored as __half (R6: halves gather bytes; accum stays fp32)
__device__ inline float4 h4_to_f4(uint2 u) {
  __half2 lo = *(__half2*)&u.x;
  __half2 hi = *(__half2*)&u.y;
  float2 a = __half22float2(lo), b = __half22float2(hi);
  return make_float4(a.x, a.y, b.x, b.y);
}
__device__ inline uint2 f4_to_h4(float4 v) {
  __half2 lo = __floats2half2_rn(v.x, v.y);
  __half2 hi = __floats2half2_rn(v.z, v.w);
  uint2 r; r.x = *(unsigned*)&lo; r.y = *(unsigned*)&hi; return r;
}

// ================= counting-sort CSR build — ZERO global atomics =================

// ---- phase 1: per-block histogram of dst bins (writes transposed: [bin][block]) ----
__global__ __launch_bounds__(256) void k_hist(const int* __restrict__ dst,
                                              unsigned* __restrict__ histG,
                                              int E, int EPB, int nbins) {
  __shared__ unsigned lh[1024];
  for (int i = threadIdx.x; i < nbins; i += 256) lh[i] = 0;
  __syncthreads();
  int start = blockIdx.x * EPB;
  int end = start + EPB; if (end > E) end = E;
  for (int e = start + threadIdx.x; e < end; e += 256)
    atomicAdd(&lh[dst[e] >> BINSHIFT], 1u);
  __syncthreads();
  for (int i = threadIdx.x; i < nbins; i += 256)
    histG[(size_t)i * GB + blockIdx.x] = lh[i];
}

// ---- phase 2a: per-bin totals (wave per bin, coalesced uint4) ----
__global__ __launch_bounds__(256) void k_scanT(const unsigned* __restrict__ histG,
                                               unsigned* __restrict__ binTot, int nbins) {
  int wave = threadIdx.x >> 6;
  int lane = threadIdx.x & 63;
  int bin = blockIdx.x * 4 + wave;
  if (bin >= nbins) return;
  uint4 v = *(const uint4*)(histG + (size_t)bin * GB + lane * 4);
  int s = (int)(v.x + v.y + v.z + v.w);
#pragma unroll
  for (int off = 32; off > 0; off >>= 1) s += __shfl_down(s, off, 64);
  if (lane == 0) binTot[bin] = (unsigned)s;
}

// ---- phase 2b: exclusive scan of bin totals (one block, 3KB in LDS) ----
__global__ __launch_bounds__(1024) void k_scanB(const unsigned* __restrict__ binTot,
                                                unsigned* __restrict__ binBase, int nbins) {
  __shared__ unsigned tot[1024];
  int b = threadIdx.x;
  tot[b] = (b < nbins) ? binTot[b] : 0;
  __syncthreads();
  for (int off = 1; off < 1024; off <<= 1) {
    unsigned v = (b >= off) ? tot[b - off] : 0;
    __syncthreads();
    tot[b] += v;
    __syncthreads();
  }
  if (b < nbins) binBase[b] = (b == 0) ? 0u : tot[b - 1];
  if (b == 0) binBase[nbins] = tot[1023];
}

// ---- phase 2c: rewrite histG to per-(block,bin) global offsets (wave per bin) ----
__global__ __launch_bounds__(256) void k_scanC(unsigned* __restrict__ histG,
                                               const unsigned* __restrict__ binBase,
                                               int nbins) {
  int wave = threadIdx.x >> 6;
  int lane = threadIdx.x & 63;
  int bin = blockIdx.x * 4 + wave;
  if (bin >= nbins) return;
  uint4 v = *(const uint4*)(histG + (size_t)bin * GB + lane * 4);
  unsigned i1 = v.x + v.y;
  unsigned i2 = i1 + v.z;
  unsigned i3 = i2 + v.w;
  int inc = (int)i3;
#pragma unroll
  for (int off = 1; off < 64; off <<= 1) {
    int t = __shfl_up(inc, off, 64);
    if (lane >= off) inc += t;
  }
  unsigned base = binBase[bin] + (unsigned)inc - i3;  // exclusive lane prefix
  uint4 o;
  o.x = base;
  o.y = base + v.x;
  o.z = base + i1;
  o.w = base + i2;
  *(uint4*)(histG + (size_t)bin * GB + lane * 4) = o;
}

// ---- phase 3: scatter edges to bin-sorted order (LDS ranks only) ----
// packed record: .x = src | (dstLow7 << 24)   (src < 2^24), .y = weight bits
__global__ __launch_bounds__(256) void k_scatter(const int* __restrict__ src,
                                                 const int* __restrict__ dst,
                                                 const float* __restrict__ ew,
                                                 const unsigned* __restrict__ histG,
                                                 uint2* __restrict__ sorted,
                                                 int E, int EPB, int nbins) {
  __shared__ unsigned lrank[1024];
  __shared__ unsigned lbase[1024];
  for (int i = threadIdx.x; i < nbins; i += 256) {
    lrank[i] = 0;
    lbase[i] = histG[(size_t)i * GB + blockIdx.x];
  }
  __syncthreads();
  int start = blockIdx.x * EPB;
  int end = start + EPB; if (end > E) end = E;
  for (int e = start + threadIdx.x; e < end; e += 256) {
    int d = dst[e];
    int bin = d >> BINSHIFT;
    unsigned r = atomicAdd(&lrank[bin], 1u);
    uint2 rec;
    rec.x = (unsigned)src[e] | ((unsigned)(d & 127) << 24);
    rec.y = __float_as_uint(ew[e]);
    sorted[lbase[bin] + r] = rec;
  }
}

// ---- phase 4: per-bin padded-CSR fill + cnt + dis, LDS only; zero-pads [cnt,64) ----
__global__ __launch_bounds__(256) void k_csr(const uint2* __restrict__ sorted,
                                             const unsigned* __restrict__ binBase,
                                             unsigned* __restrict__ cnt,
                                             EdgeRec* __restrict__ ep,
                                             float* __restrict__ dis, int N) {
  int bin = blockIdx.x;
  __shared__ unsigned lcnt[128];
  __shared__ float lsum[128];
  if (threadIdx.x < 128) { lcnt[threadIdx.x] = 0; lsum[threadIdx.x] = 0.f; }
  __syncthreads();
  unsigned s0 = binBase[bin], s1 = binBase[bin + 1];
  int node0 = bin << BINSHIFT;
  for (unsigned e = s0 + threadIdx.x; e < s1; e += 256) {
    uint2 rec = sorted[e];
    int dlow = rec.x >> 24;
    int srcn = rec.x & 0xFFFFFF;
    unsigned slot = atomicAdd(&lcnt[dlow], 1u);
    if (slot < CAP) {
      EdgeRec r; r.x = srcn; r.y = (int)rec.y;
      ep[(size_t)(node0 + dlow) * CAP + slot] = r;
    }
    atomicAdd(&lsum[dlow], __uint_as_float(rec.y));
  }
  __syncthreads();
  // zero-pad slots [cnt, 64): gather kernels then need no weight gates (pad w = 0)
  for (int i = threadIdx.x; i < 128 * CAP; i += 256) {
    int dlow = i >> 6;
    int slot = i & (CAP - 1);
    int node = node0 + dlow;
    unsigned c = lcnt[dlow]; if (c > CAP) c = CAP;
    if (node < N && (unsigned)slot >= c) {
      EdgeRec zr; zr.x = 0; zr.y = 0;
      ep[(size_t)node * CAP + slot] = zr;
    }
  }
  if (threadIdx.x < 128) {
    int node = node0 + threadIdx.x;
    if (node < N) {
      unsigned c = lcnt[threadIdx.x]; if (c > CAP) c = CAP;
      cnt[node] = c;
      dis[node] = 1.0f / sqrtf(1.0f + lsum[threadIdx.x]);
    }
  }
}

// fold dis[src] into stored edge weight (pad slots untouched: lane < cnt only)
__global__ __launch_bounds__(256) void k_premul(EdgeRec* __restrict__ ep,
                                                const unsigned* __restrict__ cnt,
                                                const float* __restrict__ dis, int N) {
  int wave = threadIdx.x >> 6;
  int lane = threadIdx.x & 63;
  int node = blockIdx.x * 4 + wave;
  if (node >= N) return;
  int c = (int)cnt[node];
  if (lane < c) {
    int e = node * CAP + lane;
    EdgeRec r = ep[e];
    r.y = __float_as_int(dis[r.x] * __int_as_float(r.y));
    ep[e] = r;
  }
}

// ---------------- pure GEMM layer-1 ----------------

__global__ __launch_bounds__(1024) void k_gemm1(const float* __restrict__ X,
                                                const float* __restrict__ W,
                                                __half* __restrict__ Y,
                                                int N, int numTiles) {
  __shared__ float sW[128 * 128];  // 64 KB, [k][c]
  __shared__ float sX[128 * 128];  // 64 KB, [r][k ^ ((r>>2)&7)<<2]
  int t = threadIdx.x;
  int wave = __builtin_amdgcn_readfirstlane(t >> 6);  // 0..15
  int lane = t & 63;
  int lr = (lane >> 3) & 7;
  int lc = lane & 7;
  int wr = wave >> 2;  // 0..3
  int wc = wave & 3;   // 0..3

  {
    const float4* W4 = (const float4*)W;
    float4* sW4 = (float4*)sW;
    for (int i = t; i < 4096; i += 1024) sW4[i] = W4[i];
  }

  const float4* X4 = (const float4*)X;
  int grmax = N - 1;
  int r0 = wr * 32 + lr * 4;   // 4 rows per thread
  int c0 = wc * 32 + lc * 4;   // 4 cols per thread
  int swzk = ((r0 >> 2) & 7) << 2;

  for (int tile = blockIdx.x; tile < numTiles; tile += gridDim.x) {
    int rowBase = tile * 128;
    __syncthreads();  // prior tile's sX reads done
    {
      int kg = t & 31;
      int rb = t >> 5;
#pragma unroll
      for (int p = 0; p < 4; p++) {
        int r = rb + 32 * p;
        int gr = rowBase + r; if (gr > grmax) gr = grmax;
        float4 v = X4[(size_t)gr * 32 + kg];
        int swz = ((r >> 2) & 7) << 2;
        *(float4*)(&sX[r * 128 + ((kg * 4) ^ swz)]) = v;
      }
    }
    __syncthreads();

    float4 acc[4];
#pragma unroll
    for (int i = 0; i < 4; i++) acc[i] = make_float4(0.f, 0.f, 0.f, 0.f);

#pragma unroll 1
    for (int kg = 0; kg < 32; kg++) {
      int kk0 = kg * 4;
      float4 xf[4];
#pragma unroll
      for (int i = 0; i < 4; i++)
        xf[i] = *(const float4*)(&sX[(r0 + i) * 128 + (kk0 ^ swzk)]);
      float4 wf[4];
#pragma unroll
      for (int kk = 0; kk < 4; kk++)
        wf[kk] = *(const float4*)(&sW[(kk0 + kk) * 128 + c0]);
#pragma unroll
      for (int kk = 0; kk < 4; kk++) {
#pragma unroll
        for (int i = 0; i < 4; i++) {
          float xs = (&xf[i].x)[kk];
          acc[i].x = fmaf(xs, wf[kk].x, acc[i].x);
          acc[i].y = fmaf(xs, wf[kk].y, acc[i].y);
          acc[i].z = fmaf(xs, wf[kk].z, acc[i].z);
          acc[i].w = fmaf(xs, wf[kk].w, acc[i].w);
        }
      }
    }

#pragma unroll
    for (int i = 0; i < 4; i++) {
      int row = rowBase + r0 + i;
      if (row < N)
        *(uint2*)(Y + (size_t)row * 128 + c0) = f4_to_h4(acc[i]);
    }
  }
}

// ---------------- fused: layer-1 aggregate -> LDS tile -> GEMM by W2 ----------------
// R13: R10's half-wave-per-node depth-3 pipeline (16 rows in flight per wave — the MLP
// R12 destroyed) + zero-pad VALU strips (no weight gates, 1-op min clamp). R12 proved
// VALU alone isn't binding (VALUBusy 53->41 but slower); MLP is co-binding.

__global__ __launch_bounds__(1024) void k_aggemm(const __half* __restrict__ H,
                                                 const unsigned* __restrict__ cntA,
                                                 const EdgeRec* __restrict__ ep,
                                                 const float* __restrict__ dis,
                                                 const float* __restrict__ bias,
                                                 const float* __restrict__ Wm,
                                                 __half* __restrict__ Y,
                                                 int N, int numTiles) {
  __shared__ float sW[128 * 128];     // 64 KB, [k][c]
  __shared__ float sX[2][64 * 128];   // 2 x 32 KB, [r][k ^ ((r>>2)&7)<<2]
  int t = threadIdx.x;
  int wave = __builtin_amdgcn_readfirstlane(t >> 6);  // 0..15
  int lane = t & 63;

  {
    const float4* W4 = (const float4*)Wm;
    float4* sW4 = (float4*)sW;
    for (int i = t; i < 4096; i += 1024) sW4[i] = W4[i];
  }
  __syncthreads();

  int gw = wave;
  int half = lane >> 5;
  int l32 = lane & 31;
  int mw = wave - 12;
  int wr = (mw >> 1) & 1;
  int wc = mw & 1;
  int lr = (lane >> 3) & 7;
  int lc = lane & 7;
  int rB = wr * 32 + lr * 4;
  int cA = wc * 64 + lc * 4;
  int cB = cA + 32;
  int swzm = lr << 2;
  int s2b = 2 * gw;

  for (int it = 0;; it++) {
    int gtile = blockIdx.x + it * gridDim.x;
    int mtile = gtile - (int)gridDim.x;
    bool anyG = gtile < numTiles;
    bool anyM = (it >= 1) && (mtile < numTiles);
    if (!anyG && !anyM) break;

    if (wave < 12) {
      if (anyG) {
        float* buf = sX[it & 1];
        int tileBase = gtile * 64;
        // prefetch counts for this wave's (up to 3) node-pairs, batched
        int cnts[3];
#pragma unroll
        for (int k = 0; k < 3; k++) {
          int s2 = s2b + 24 * k;
          int node = tileBase + s2 + half;
          int nodec = node < N ? node : N - 1;
          unsigned pk = cntA[nodec];
          cnts[k] = (s2 < 64 && node < N) ? (int)pk : 0;
        }
#pragma unroll 1
        for (int k = 0; k < 3; k++) {
          int s2 = s2b + 24 * k;
          if (s2 >= 64) break;
          int node = tileBase + s2 + half;
          int cnt = cnts[k];  // 0 if node >= N
          int beg = (node < N ? node : 0) * CAP;
          int emax = beg + CAP - 1;

          float4 acc = make_float4(0.f, 0.f, 0.f, 0.f);
          if (cnt > 0) {
            EdgeRec e0[4], e1[4], e2[4], e3[4];
            uint2 h0[4], h1[4];
#pragma unroll
            for (int q = 0; q < 4; q++) e0[q] = ep[min(beg + q, emax)];
#pragma unroll
            for (int q = 0; q < 4; q++) e1[q] = ep[min(beg + 4 + q, emax)];
#pragma unroll
            for (int q = 0; q < 4; q++) e2[q] = ep[min(beg + 8 + q, emax)];
#pragma unroll
            for (int q = 0; q < 4; q++)
              h0[q] = *(const uint2*)(H + (size_t)e0[q].x * 128 + 4 * l32);
#pragma unroll
            for (int q = 0; q < 4; q++)
              h1[q] = *(const uint2*)(H + (size_t)e1[q].x * 128 + 4 * l32);
#pragma unroll 2
            for (int p = 0; p < cnt; p += 4) {
              uint2 h2[4];
#pragma unroll
              for (int q = 0; q < 4; q++)
                e3[q] = ep[min(beg + p + 12 + q, emax)];
#pragma unroll
              for (int q = 0; q < 4; q++)
                h2[q] = *(const uint2*)(H + (size_t)e2[q].x * 128 + 4 * l32);
#pragma unroll
              for (int q = 0; q < 4; q++) {
                float w = __int_as_float(e0[q].y);   // pads: w = 0
                float4 hv = h4_to_f4(h0[q]);
                acc.x = fmaf(w, hv.x, acc.x);
                acc.y = fmaf(w, hv.y, acc.y);
                acc.z = fmaf(w, hv.z, acc.z);
                acc.w = fmaf(w, hv.w, acc.w);
              }
#pragma unroll
              for (int q = 0; q < 4; q++) {
                e0[q] = e1[q]; e1[q] = e2[q]; e2[q] = e3[q];
                h0[q] = h1[q]; h1[q] = h2[q];
              }
            }
          }
          if (node < N) {
            float ds = dis[node];
            float4 hn = h4_to_f4(*(const uint2*)(H + (size_t)node * 128 + 4 * l32));
            acc.x = fmaf(ds, hn.x, acc.x);
            acc.y = fmaf(ds, hn.y, acc.y);
            acc.z = fmaf(ds, hn.z, acc.z);
            acc.w = fmaf(ds, hn.w, acc.w);
            float4 bv = *(const float4*)(bias + 4 * l32);
            float4 o;
            o.x = fmaf(ds, acc.x, bv.x); o.x = o.x > 0.f ? o.x : 0.f;
            o.y = fmaf(ds, acc.y, bv.y); o.y = o.y > 0.f ? o.y : 0.f;
            o.z = fmaf(ds, acc.z, bv.z); o.z = o.z > 0.f ? o.z : 0.f;
            o.w = fmaf(ds, acc.w, bv.w); o.w = o.w > 0.f ? o.w : 0.f;
            int s = s2 + half;
            int swz = ((s >> 2) & 7) << 2;
            *(float4*)(&buf[s * 128 + ((4 * l32) ^ swz)]) = o;
          }
        }
      }
    } else {
      if (anyM) {
        const float* buf = sX[(it - 1) & 1];
        float4 accA[4], accB[4];
#pragma unroll
        for (int i = 0; i < 4; i++) {
          accA[i] = make_float4(0.f, 0.f, 0.f, 0.f);
          accB[i] = make_float4(0.f, 0.f, 0.f, 0.f);
        }
#pragma unroll 2
        for (int kg = 0; kg < 32; kg++) {
          int kk0 = kg * 4;
          float4 xf[4];
#pragma unroll
          for (int i = 0; i < 4; i++)
            xf[i] = *(const float4*)(&buf[(rB + i) * 128 + (kk0 ^ swzm)]);
#pragma unroll
          for (int kk = 0; kk < 4; kk++) {
            float4 wA = *(const float4*)(&sW[(kk0 + kk) * 128 + cA]);
            float4 wB = *(const float4*)(&sW[(kk0 + kk) * 128 + cB]);
#pragma unroll
            for (int i = 0; i < 4; i++) {
              float xs = (&xf[i].x)[kk];
              accA[i].x = fmaf(xs, wA.x, accA[i].x);
              accA[i].y = fmaf(xs, wA.y, accA[i].y);
              accA[i].z = fmaf(xs, wA.z, accA[i].z);
              accA[i].w = fmaf(xs, wA.w, accA[i].w);
              accB[i].x = fmaf(xs, wB.x, accB[i].x);
              accB[i].y = fmaf(xs, wB.y, accB[i].y);
              accB[i].z = fmaf(xs, wB.z, accB[i].z);
              accB[i].w = fmaf(xs, wB.w, accB[i].w);
            }
          }
        }
        int rowBase = mtile * 64;
#pragma unroll
        for (int i = 0; i < 4; i++) {
          int row = rowBase + rB + i;
          if (row < N) {
            *(uint2*)(Y + (size_t)row * 128 + cA) = f4_to_h4(accA[i]);
            *(uint2*)(Y + (size_t)row * 128 + cB) = f4_to_h4(accB[i]);
          }
        }
      }
    }
    __syncthreads();
  }
}

// ---- final aggregate fused with W3 dot: z[node] = relu(dis*(agg + dis*h_own) + b2) . W3 ----
// R13: R10's half-wave-per-node (8 nodes / 256-thread block) + zero-pad VALU strips.

__global__ __launch_bounds__(256) void k_agg_final(const __half* __restrict__ H,
                                                   const unsigned* __restrict__ cntA,
                                                   const EdgeRec* __restrict__ ep,
                                                   const float* __restrict__ dis,
                                                   const float* __restrict__ bias,
                                                   const float* __restrict__ W3,
                                                   float* __restrict__ z, int N) {
  int wave = __builtin_amdgcn_readfirstlane(threadIdx.x >> 6);
  int lane = threadIdx.x & 63;
  int half = lane >> 5;
  int l32  = lane & 31;
  int node = blockIdx.x * 8 + wave * 2 + half;
  int nodec = node < N ? node : N - 1;
  int cnt = (node < N) ? (int)cntA[nodec] : 0;
  int beg = nodec * CAP;
  int emax = beg + CAP - 1;

  float4 acc = make_float4(0.f, 0.f, 0.f, 0.f);
  if (cnt > 0) {
    EdgeRec e0[4], e1[4], e2[4];
    uint2 h0[4], h1[4];
#pragma unroll
    for (int q = 0; q < 4; q++) e0[q] = ep[min(beg + q, emax)];
#pragma unroll
    for (int q = 0; q < 4; q++) e1[q] = ep[min(beg + 4 + q, emax)];
#pragma unroll
    for (int q = 0; q < 4; q++)
      h0[q] = *(const uint2*)(H + (size_t)e0[q].x * 128 + 4 * l32);
#pragma unroll 2
    for (int p = 0; p < cnt; p += 4) {
      uint2 h1n[4];
#pragma unroll
      for (int q = 0; q < 4; q++)
        e2[q] = ep[min(beg + p + 8 + q, emax)];
#pragma unroll
      for (int q = 0; q < 4; q++)
        h1n[q] = *(const uint2*)(H + (size_t)e1[q].x * 128 + 4 * l32);
#pragma unroll
      for (int q = 0; q < 4; q++) {
        float w = __int_as_float(e0[q].y);   // pads: w = 0
        float4 hv = h4_to_f4(h0[q]);
        acc.x = fmaf(w, hv.x, acc.x);
        acc.y = fmaf(w, hv.y, acc.y);
        acc.z = fmaf(w, hv.z, acc.z);
        acc.w = fmaf(w, hv.w, acc.w);
      }
#pragma unroll
      for (int q = 0; q < 4; q++) { e0[q] = e1[q]; e1[q] = e2[q]; h0[q] = h1n[q]; }
    }
  }
  float ds = dis[nodec];
  float4 hn = h4_to_f4(*(const uint2*)(H + (size_t)nodec * 128 + 4 * l32));
  acc.x = fmaf(ds, hn.x, acc.x);
  acc.y = fmaf(ds, hn.y, acc.y);
  acc.z = fmaf(ds, hn.z, acc.z);
  acc.w = fmaf(ds, hn.w, acc.w);
  float4 bv = *(const float4*)(bias + 4 * l32);
  float4 w3v = *(const float4*)(W3 + 4 * l32);
  float o, pdot = 0.f;
  o = fmaf(ds, acc.x, bv.x); o = o > 0.f ? o : 0.f; pdot = fmaf(o, w3v.x, pdot);
  o = fmaf(ds, acc.y, bv.y); o = o > 0.f ? o : 0.f; pdot = fmaf(o, w3v.y, pdot);
  o = fmaf(ds, acc.z, bv.z); o = o > 0.f ? o : 0.f; pdot = fmaf(o, w3v.z, pdot);
  o = fmaf(ds, acc.w, bv.w); o = o > 0.f ? o : 0.f; pdot = fmaf(o, w3v.w, pdot);
#pragma unroll
  for (int off = 16; off > 0; off >>= 1) pdot += __shfl_down(pdot, off, 32);
  if (l32 == 0 && node < N) z[node] = pdot;
}

// ---------------- scalar final layer: out = relu(dis*(agg_z + dis*z[n]) + b3) ----------------

__global__ void k_aggs(const float* __restrict__ z, const unsigned* __restrict__ cntA,
                       const EdgeRec* __restrict__ ep, const float* __restrict__ dis,
                       const float* __restrict__ b3, float* __restrict__ out, int N) {
  int n = blockIdx.x * blockDim.x + threadIdx.x;
  if (n >= N) return;
  int cnt = (int)cntA[n];
  float dsn = dis[n];
  float acc = dsn * z[n];  // self-loop
  int beg = n * CAP;
#pragma unroll 4
  for (int e = beg; e < beg + cnt; e++) {
    EdgeRec p = ep[e];
    acc = fmaf(__int_as_float(p.y), z[p.x], acc);
  }
  acc = fmaf(dsn, acc, b3[0]);
  out[n] = acc > 0.f ? acc : 0.f;
}

// ---------------- launch ----------------

extern "C" void kernel_launch(void* const* d_in, const int* in_sizes, int n_in,
                              void* d_out, int out_size, void* d_ws, size_t ws_size,
                              hipStream_t stream) {
  const float* x  = (const float*)d_in[0];
  const int*   ei = (const int*)d_in[1];
  const float* ew = (const float*)d_in[2];
  const float* W1 = (const float*)d_in[3];
  const float* b1 = (const float*)d_in[4];
  const float* W2 = (const float*)d_in[5];
  const float* b2 = (const float*)d_in[6];
  const float* W3 = (const float*)d_in[7];
  const float* b3 = (const float*)d_in[8];
  int N = in_sizes[0] / NFEAT;
  int E = in_sizes[2];
  const int* srcp = ei;
  const int* dstp = ei + E;

  char* p = (char*)d_ws;
  auto carve = [&](size_t bytes) -> void* {
    void* r = (void*)p;
    p += (bytes + 511) & ~(size_t)511;
    return r;
  };
  int nbins = (N + 127) >> BINSHIFT;     // 782 for N=100000 (must be <= 1024)
  unsigned* cnt     = (unsigned*)carve(sizeof(unsigned) * N);
  float*    dis     = (float*)carve(sizeof(float) * N);
  EdgeRec*  ep      = (EdgeRec*)carve(sizeof(EdgeRec) * ((size_t)N * CAP + 64));
  __half*   t1      = (__half*)carve(sizeof(__half) * (size_t)N * NFEAT);
  __half*   t2      = (__half*)carve(sizeof(__half) * (size_t)N * NFEAT);
  float*    z       = (float*)carve(sizeof(float) * N);
  unsigned* histG   = (unsigned*)carve(sizeof(unsigned) * (size_t)GB * nbins);
  unsigned* binTot  = (unsigned*)carve(sizeof(unsigned) * nbins);
  unsigned* binBase = (unsigned*)carve(sizeof(unsigned) * (nbins + 1));
  uint2*    sorted  = (uint2*)carve(sizeof(uint2) * (size_t)E);

  int gN = (N + 255) / 256;
  int numTiles128 = (N + 127) / 128;
  int numTiles64  = (N + 63) / 64;
  int GG = 256;                      // 1 block/CU grids
  int EPB = (E + GB - 1) / GB;       // edges per build block
  int gS = (nbins + 3) / 4;          // scanT/scanC: wave per bin
  int gP = (N + 3) / 4;              // k_premul: 4 nodes/block
  int gF = (N + 7) / 8;              // k_agg_final: 8 nodes/block (half-wave each)

  // counting-sort CSR build (no global atomics; R10 parallel coalesced scan)
  k_hist<<<GB, 256, 0, stream>>>(dstp, histG, E, EPB, nbins);
  k_scanT<<<gS, 256, 0, stream>>>(histG, binTot, nbins);
  k_scanB<<<1, 1024, 0, stream>>>(binTot, binBase, nbins);
  k_scanC<<<gS, 256, 0, stream>>>(histG, binBase, nbins);
  k_scatter<<<GB, 256, 0, stream>>>(srcp, dstp, ew, histG, sorted, E, EPB, nbins);
  k_csr<<<nbins, 256, 0, stream>>>(sorted, binBase, cnt, ep, dis, N);
  // layer-1 GEMM
  k_gemm1<<<GG, 1024, 0, stream>>>(x, W1, t1, N, numTiles128);
  // fold dis[src] into edge weights (used by all three aggregate kernels)
  k_premul<<<gP, 256, 0, stream>>>(ep, cnt, dis, N);
  // layer-1 aggregate fused with layer-2 GEMM (12 gather + 4 gemm waves)
  k_aggemm<<<GG, 1024, 0, stream>>>(t1, cnt, ep, dis, b1, W2, t2, N, numTiles64);
  // layer-2 aggregate + W3 dot
  k_agg_final<<<gF, 256, 0, stream>>>(t2, cnt, ep, dis, b2, W3, z, N);
  // layer-3 scalar aggregate
  k_aggs<<<gN, 256, 0, stream>>>(z, cnt, ep, dis, b3, (float*)d_out, N);
}